// Round 2
// baseline (1151.548 us; speedup 1.0000x reference)
//
#include <hip/hip_runtime.h>
#include <hip/hip_cooperative_groups.h>
#include <math.h>

namespace cg = cooperative_groups;

// TreeLSTM, complete binary tree N = 2^15-1 (implicit: children(i)=2i+1,2i+2).
// Round 5: 3-dispatch pipeline.
//  1) conv3: W_ih, W_hh AND x -> bf16 in one pass (x pre-conversion lets bulk
//     use global_load_lds for A, removing all VALU staging from the hot loop).
//  2) bulk_xw2: pure gload_lds A+B, BK=64, XOR swizzle, XCD-bijective remap.
//  3) levels_coop: ALL 14 levels + pooled mean + fc in ONE cooperative kernel
//     (grid=512, grid.sync between levels) -- replaces 7 level launches + tail
//     coop + 2 reduce launches. Level GEMM moved to BK=64 (conflict-free
//     swizzle, half the barriers). gx relaid out [node][ch][gate] (8B reads).
// Fallbacks: small-ws -> inline-conversion bulk; coop-reject -> per-level.

#define N_NODES 32767
#define N_LEAF0 16383     // first leaf node index
#define IN_C    512
#define H_C     256

typedef __bf16 bf16x8 __attribute__((ext_vector_type(8)));
typedef __bf16 bf16x4 __attribute__((ext_vector_type(4)));
typedef float  f32x4  __attribute__((ext_vector_type(4)));

__device__ __forceinline__ void gload_lds16(const void* g, void* l) {
    __builtin_amdgcn_global_load_lds(
        (const __attribute__((address_space(1))) unsigned int*)g,
        (__attribute__((address_space(3))) unsigned int*)l,
        16, 0, 0);
}

__device__ __forceinline__ float fast_rcp(float x) { return __builtin_amdgcn_rcpf(x); }
__device__ __forceinline__ float sigm(float x)     { return fast_rcp(1.f + __expf(-x)); }
__device__ __forceinline__ float tanh_fast(float x){ return 2.f * fast_rcp(1.f + __expf(-2.f * x)) - 1.f; }

// ---- fused fp32 -> bf16 converter: W_ih | W_hh | x, grid-stride ----
__global__ __launch_bounds__(256)
void conv3(const float* __restrict__ a, __bf16* __restrict__ da, int n8a,
           const float* __restrict__ b, __bf16* __restrict__ db, int n8b,
           const float* __restrict__ cx, __bf16* __restrict__ dc, int n8c)
{
    const int total = n8a + n8b + n8c;
    for (int i = blockIdx.x * 256 + threadIdx.x; i < total; i += gridDim.x * 256) {
        const float* s; __bf16* d; int j;
        if (i < n8a)              { s = a;  d = da; j = i; }
        else if (i < n8a + n8b)   { s = b;  d = db; j = i - n8a; }
        else                      { s = cx; d = dc; j = i - n8a - n8b; }
        const float4* s4 = (const float4*)s;
        const float4 v0 = s4[2 * j];
        const float4 v1 = s4[2 * j + 1];
        bf16x8 o;
        o[0] = (__bf16)v0.x; o[1] = (__bf16)v0.y; o[2] = (__bf16)v0.z; o[3] = (__bf16)v0.w;
        o[4] = (__bf16)v1.x; o[5] = (__bf16)v1.y; o[6] = (__bf16)v1.z; o[7] = (__bf16)v1.w;
        *(bf16x8*)(d + 8 * j) = o;
    }
}

// ---- bulk v2: acc = x @ W_ih^T for ALL nodes, A and B both via gload_lds ----
__global__ __launch_bounds__(256)
void bulk_xw2(const __bf16* __restrict__ xb,
              const __bf16* __restrict__ wih,
              const float* __restrict__ b_ih,
              const float* __restrict__ b_hh,
              __bf16* __restrict__ hb,
              float* __restrict__ c,
              __bf16* __restrict__ gx)
{
    __shared__ __bf16 As[128 * 64];   // linear dest, source pre-swizzled
    __shared__ __bf16 Bs[128 * 64];

    const int t    = threadIdx.x;
    const int lane = t & 63;
    const int wv   = t >> 6;
    const int wm   = wv >> 1;
    const int wn   = wv & 1;
    const int quad = lane >> 4;
    const int l15  = lane & 15;

    const int i  = blockIdx.x;
    const int cb = (i >> 3) & 7;
    const int mt = (i & 7) | ((i >> 6) << 3);
    const int m0 = mt * 128;

    f32x4 acc[4][4];
#pragma unroll
    for (int mi = 0; mi < 4; ++mi)
#pragma unroll
        for (int ni = 0; ni < 4; ++ni) acc[mi][ni] = (f32x4)0.f;

    for (int k0 = 0; k0 < IN_C; k0 += 64) {
#pragma unroll
        for (int e = 0; e < 4; ++e) {
            const int ch = (wv * 4 + e) * 64 + lane;
            const int nl = ch >> 3;
            const int k8 = (ch & 7) ^ (nl & 7);
            // B: W_ih rows
            const int q  = (nl >> 4) & 3;
            const int cc = (nl & 15) | ((nl >> 6) << 4);
            const int grow = q * H_C + cb * 32 + cc;
            gload_lds16(wih + (size_t)grow * IN_C + k0 + k8 * 8,
                        (char*)Bs + (wv * 4 + e) * 1024);
            // A: xb rows (clamp last tile's row 32767 -> 32766, epilogue skips)
            int node = m0 + nl; if (node > N_NODES - 1) node = N_NODES - 1;
            gload_lds16(xb + (size_t)node * IN_C + k0 + k8 * 8,
                        (char*)As + (wv * 4 + e) * 1024);
        }
        __syncthreads();
#pragma unroll
        for (int ks = 0; ks < 2; ++ks) {
            bf16x8 af[4], bfr[4];
#pragma unroll
            for (int mi = 0; mi < 4; ++mi) {
                const int row = wm * 64 + mi * 16 + l15;
                af[mi] = *(const bf16x8*)(As + row * 64 + (((ks * 4 + quad) ^ (row & 7)) << 3));
            }
#pragma unroll
            for (int ni = 0; ni < 4; ++ni) {
                const int row = wn * 64 + ni * 16 + l15;
                bfr[ni] = *(const bf16x8*)(Bs + row * 64 + (((ks * 4 + quad) ^ (row & 7)) << 3));
            }
#pragma unroll
            for (int mi = 0; mi < 4; ++mi)
#pragma unroll
                for (int ni = 0; ni < 4; ++ni)
                    acc[mi][ni] = __builtin_amdgcn_mfma_f32_16x16x32_bf16(
                        af[mi], bfr[ni], acc[mi][ni], 0, 0, 0);
        }
        __syncthreads();
    }

    const int CH = cb * 32 + wn * 16 + l15;
    float bs4[4];
#pragma unroll
    for (int q = 0; q < 4; ++q) bs4[q] = b_ih[q * H_C + CH] + b_hh[q * H_C + CH];

#pragma unroll
    for (int mi = 0; mi < 4; ++mi) {
#pragma unroll
        for (int r = 0; r < 4; ++r) {
            const int m = m0 + wm * 64 + mi * 16 + quad * 4 + r;
            if (m >= N_NODES) continue;
            if (m >= N_LEAF0) {
                const float gi = sigm(acc[mi][0][r] + bs4[0]);
                const float gg = tanh_fast(acc[mi][2][r] + bs4[2]);
                const float go = sigm(acc[mi][3][r] + bs4[3]);
                const float cn = gi * gg;
                const float hn = go * tanh_fast(cn);
                c[(size_t)m * H_C + CH] = cn;
                hb[(size_t)m * H_C + CH] = (__bf16)hn;
            } else {
                bf16x4 o;
#pragma unroll
                for (int q = 0; q < 4; ++q) o[q] = (__bf16)acc[mi][q][r];
                *(bf16x4*)(gx + ((size_t)m * H_C + CH) * 4) = o;
            }
        }
    }
}

// ---- bulk fallback (small ws): inline fp32->bf16 A-staging (round-1 code) ----
__global__ __launch_bounds__(256)
void bulk_xw(const float* __restrict__ x,
             const __bf16* __restrict__ wih,
             const float* __restrict__ b_ih,
             const float* __restrict__ b_hh,
             __bf16* __restrict__ hb,
             float* __restrict__ c,
             __bf16* __restrict__ gx)
{
    __shared__ __bf16 As[128 * 64];
    __shared__ __bf16 Bs[128 * 64];

    const int t    = threadIdx.x;
    const int lane = t & 63;
    const int wv   = t >> 6;
    const int wm   = wv >> 1;
    const int wn   = wv & 1;
    const int quad = lane >> 4;
    const int l15  = lane & 15;

    const int i  = blockIdx.x;
    const int cb = (i >> 3) & 7;
    const int mt = (i & 7) | ((i >> 6) << 3);
    const int m0 = mt * 128;

    f32x4 acc[4][4];
#pragma unroll
    for (int mi = 0; mi < 4; ++mi)
#pragma unroll
        for (int ni = 0; ni < 4; ++ni) acc[mi][ni] = (f32x4)0.f;

    for (int k0 = 0; k0 < IN_C; k0 += 64) {
#pragma unroll
        for (int e = 0; e < 4; ++e) {
            const int ch = (wv * 4 + e) * 64 + lane;
            const int nl = ch >> 3;
            const int k8 = (ch & 7) ^ (nl & 7);
            const int q  = (nl >> 4) & 3;
            const int cc = (nl & 15) | ((nl >> 6) << 4);
            const int grow = q * H_C + cb * 32 + cc;
            gload_lds16(wih + (size_t)grow * IN_C + k0 + k8 * 8,
                        (char*)Bs + (wv * 4 + e) * 1024);
        }
        {
            const int row  = t >> 1;
            const int kh   = (t & 1) * 32;
            const int node = min(m0 + row, N_NODES - 1);
            const float4* xs = (const float4*)(x + (size_t)node * IN_C + k0 + kh);
#pragma unroll
            for (int j = 0; j < 4; ++j) {
                const float4 v0 = xs[2 * j], v1 = xs[2 * j + 1];
                bf16x8 o;
                o[0] = (__bf16)v0.x; o[1] = (__bf16)v0.y; o[2] = (__bf16)v0.z; o[3] = (__bf16)v0.w;
                o[4] = (__bf16)v1.x; o[5] = (__bf16)v1.y; o[6] = (__bf16)v1.z; o[7] = (__bf16)v1.w;
                const int cs = ((kh >> 3) + j) ^ (row & 7);
                *(bf16x8*)(As + row * 64 + cs * 8) = o;
            }
        }
        __syncthreads();
#pragma unroll
        for (int ks = 0; ks < 2; ++ks) {
            bf16x8 af[4], bfr[4];
#pragma unroll
            for (int mi = 0; mi < 4; ++mi) {
                const int row = wm * 64 + mi * 16 + l15;
                af[mi] = *(const bf16x8*)(As + row * 64 + (((ks * 4 + quad) ^ (row & 7)) << 3));
            }
#pragma unroll
            for (int ni = 0; ni < 4; ++ni) {
                const int row = wn * 64 + ni * 16 + l15;
                bfr[ni] = *(const bf16x8*)(Bs + row * 64 + (((ks * 4 + quad) ^ (row & 7)) << 3));
            }
#pragma unroll
            for (int mi = 0; mi < 4; ++mi)
#pragma unroll
                for (int ni = 0; ni < 4; ++ni)
                    acc[mi][ni] = __builtin_amdgcn_mfma_f32_16x16x32_bf16(
                        af[mi], bfr[ni], acc[mi][ni], 0, 0, 0);
        }
        __syncthreads();
    }

    const int CH = cb * 32 + wn * 16 + l15;
    float bs4[4];
#pragma unroll
    for (int q = 0; q < 4; ++q) bs4[q] = b_ih[q * H_C + CH] + b_hh[q * H_C + CH];

#pragma unroll
    for (int mi = 0; mi < 4; ++mi) {
#pragma unroll
        for (int r = 0; r < 4; ++r) {
            const int m = m0 + wm * 64 + mi * 16 + quad * 4 + r;
            if (m >= N_NODES) continue;
            if (m >= N_LEAF0) {
                const float gi = sigm(acc[mi][0][r] + bs4[0]);
                const float gg = tanh_fast(acc[mi][2][r] + bs4[2]);
                const float go = sigm(acc[mi][3][r] + bs4[3]);
                const float cn = gi * gg;
                const float hn = go * tanh_fast(cn);
                c[(size_t)m * H_C + CH] = cn;
                hb[(size_t)m * H_C + CH] = (__bf16)hn;
            } else {
                bf16x4 o;
#pragma unroll
                for (int q = 0; q < 4; ++q) o[q] = (__bf16)acc[mi][q][r];
                *(bf16x4*)(gx + ((size_t)m * H_C + CH) * 4) = o;
            }
        }
    }
}

// ---- one level-tile: gates = gates_x + mean_h @ W_hh^T (K=256, BK=64) ----
__device__ __forceinline__ void level_tile(
    const __bf16* __restrict__ whh, const float* __restrict__ b_ih,
    const float* __restrict__ b_hh, const __bf16* __restrict__ gx,
    __bf16* __restrict__ hb, float* __restrict__ c,
    __bf16* As, __bf16* Bs, int lo, int n, int cb, int m0)
{
    const int t    = threadIdx.x;
    const int lane = t & 63;
    const int wv   = t >> 6;
    const int wm   = wv >> 1;
    const int wn   = wv & 1;
    const int quad = lane >> 4;
    const int l15  = lane & 15;

    f32x4 acc[4][4];
#pragma unroll
    for (int mi = 0; mi < 4; ++mi)
#pragma unroll
        for (int ni = 0; ni < 4; ++ni) acc[mi][ni] = (f32x4)0.f;

    for (int k0 = 0; k0 < H_C; k0 += 64) {
        // B: W_hh rows, gload_lds with pre-swizzled source
#pragma unroll
        for (int e = 0; e < 4; ++e) {
            const int ch = (wv * 4 + e) * 64 + lane;
            const int nl = ch >> 3;
            const int k8 = (ch & 7) ^ (nl & 7);
            const int q  = (nl >> 4) & 3;
            const int cc = (nl & 15) | ((nl >> 6) << 4);
            const int grow = q * H_C + cb * 32 + cc;
            gload_lds16(whh + (size_t)grow * H_C + k0 + k8 * 8,
                        (char*)Bs + (wv * 4 + e) * 1024);
        }
        // A: mean of children h (bf16), XOR-swizzled ds_write
        {
            const int row  = t >> 1;
            const int kh   = (t & 1) * 32;
            const int node = lo + m0 + row;
            const int k2   = k0 + kh;
            const bf16x8* hl = (const bf16x8*)(hb + (size_t)(2 * node + 1) * H_C + k2);
            const bf16x8* hr = (const bf16x8*)(hb + (size_t)(2 * node + 2) * H_C + k2);
#pragma unroll
            for (int j = 0; j < 4; ++j) {
                const bf16x8 a = hl[j], b = hr[j];
                bf16x8 o;
#pragma unroll
                for (int e2 = 0; e2 < 8; ++e2)
                    o[e2] = (__bf16)(0.5f * ((float)a[e2] + (float)b[e2]));
                const int cs = ((kh >> 3) + j) ^ (row & 7);
                *(bf16x8*)(As + row * 64 + cs * 8) = o;
            }
        }
        __syncthreads();
#pragma unroll
        for (int ks = 0; ks < 2; ++ks) {
            bf16x8 af[4], bfr[4];
#pragma unroll
            for (int mi = 0; mi < 4; ++mi) {
                const int row = wm * 64 + mi * 16 + l15;
                af[mi] = *(const bf16x8*)(As + row * 64 + (((ks * 4 + quad) ^ (row & 7)) << 3));
            }
#pragma unroll
            for (int ni = 0; ni < 4; ++ni) {
                const int row = wn * 64 + ni * 16 + l15;
                bfr[ni] = *(const bf16x8*)(Bs + row * 64 + (((ks * 4 + quad) ^ (row & 7)) << 3));
            }
#pragma unroll
            for (int mi = 0; mi < 4; ++mi)
#pragma unroll
                for (int ni = 0; ni < 4; ++ni)
                    acc[mi][ni] = __builtin_amdgcn_mfma_f32_16x16x32_bf16(
                        af[mi], bfr[ni], acc[mi][ni], 0, 0, 0);
        }
        __syncthreads();
    }

    const int CH = cb * 32 + wn * 16 + l15;
    float bs4[4];
#pragma unroll
    for (int q = 0; q < 4; ++q) bs4[q] = b_ih[q * H_C + CH] + b_hh[q * H_C + CH];

#pragma unroll
    for (int mi = 0; mi < 4; ++mi) {
#pragma unroll
        for (int r = 0; r < 4; ++r) {
            const int m = m0 + wm * 64 + mi * 16 + quad * 4 + r;
            if (m < n) {
                const int node = lo + m;
                const bf16x4 gv = *(const bf16x4*)(gx + ((size_t)node * H_C + CH) * 4);
                const float gi = sigm(acc[mi][0][r] + (float)gv[0] + bs4[0]);
                const float gf = sigm(acc[mi][1][r] + (float)gv[1] + bs4[1]);
                const float gg = tanh_fast(acc[mi][2][r] + (float)gv[2] + bs4[2]);
                const float go = sigm(acc[mi][3][r] + (float)gv[3] + bs4[3]);
                const float mc = 0.5f * (c[(size_t)(2 * node + 1) * H_C + CH] +
                                         c[(size_t)(2 * node + 2) * H_C + CH]);
                const float cn = gf * mc + gi * gg;
                const float hn = go * tanh_fast(cn);
                c[(size_t)node * H_C + CH] = cn;
                hb[(size_t)node * H_C + CH] = (__bf16)hn;
            }
        }
    }
}

// ---- fallback standalone per-level kernel ----
__global__ __launch_bounds__(256)
void level_hw(const __bf16* __restrict__ whh,
              const float* __restrict__ b_ih,
              const float* __restrict__ b_hh,
              const __bf16* __restrict__ gx,
              __bf16* __restrict__ hb,
              float* __restrict__ c,
              int lo, int n)
{
    __shared__ __bf16 As[128 * 64];
    __shared__ __bf16 Bs[128 * 64];
    const int i = blockIdx.x;
    int cb, mt;
    if (gridDim.x >= 64) { cb = (i >> 3) & 7; mt = (i & 7) | ((i >> 6) << 3); }
    else                 { cb = i & 7;        mt = i >> 3; }
    level_tile(whh, b_ih, b_hh, gx, hb, c, As, Bs, lo, n, cb, mt * 128);
}

// ---- THE cooperative kernel: all 14 levels + pooled mean + fc ----
__global__ __launch_bounds__(256)
void levels_coop(const __bf16* __restrict__ whh,
                 const float* __restrict__ b_ih,
                 const float* __restrict__ b_hh,
                 const __bf16* __restrict__ gx,
                 __bf16* __restrict__ hb,
                 float* __restrict__ c,
                 const float* __restrict__ W_fc,
                 const float* __restrict__ b_fc,
                 float* __restrict__ part,
                 float* __restrict__ out)
{
    __shared__ __bf16 As[128 * 64];
    __shared__ __bf16 Bs[128 * 64];

    cg::grid_group grid = cg::this_grid();
    const int t  = threadIdx.x;
    const int ib = blockIdx.x;

    for (int d = 13; d >= 0; --d) {
        const int n    = 1 << d;
        const int lo   = n - 1;
        const int nblk = ((n + 127) / 128) * 8;
        if (ib < nblk) {
            int cb, mt;
            if (nblk >= 64) { cb = (ib >> 3) & 7; mt = (ib & 7) | ((ib >> 6) << 3); }
            else            { cb = ib & 7;        mt = ib >> 3; }
            level_tile(whh, b_ih, b_hh, gx, hb, c, As, Bs, lo, n, cb, mt * 128);
        }
        grid.sync();   // h,c of level d visible device-wide before level d-1
    }

    // ---- pooled mean partials: blocks 0..255, 128 rows each ----
    if (ib < 256) {
        const int rg = t >> 5;
        const int c8 = (t & 31) * 8;
        float s[8];
#pragma unroll
        for (int j = 0; j < 8; ++j) s[j] = 0.f;
        for (int i2 = 0; i2 < 16; ++i2) {
            const int row = ib * 128 + i2 * 8 + rg;
            if (row < N_NODES) {
                const bf16x8 v = *(const bf16x8*)(hb + (size_t)row * H_C + c8);
#pragma unroll
                for (int j = 0; j < 8; ++j) s[j] += (float)v[j];
            }
        }
        __shared__ float sm[8][256];
#pragma unroll
        for (int j = 0; j < 8; ++j) sm[rg][c8 + j] = s[j];
        __syncthreads();
        float tot = 0.f;
#pragma unroll
        for (int g = 0; g < 8; ++g) tot += sm[g][t];
        part[ib * H_C + t] = tot;
    }
    grid.sync();

    if (ib == 0) {
        float s = 0.f;
        for (int j = 0; j < 256; ++j) s += part[j * H_C + t];
        s = s * (1.0f / (float)N_NODES) * W_fc[t];
        __shared__ float fm[256];
        fm[t] = s;
        __syncthreads();
        for (int st = 128; st > 0; st >>= 1) {
            if (t < st) fm[t] += fm[t + st];
            __syncthreads();
        }
        if (t == 0) out[0] = fm[0] + b_fc[0];
    }
}

// ---- fallback reduce kernels ----
__global__ __launch_bounds__(256)
void reduce_rows(const __bf16* __restrict__ hb, float* __restrict__ part)
{
    __shared__ float sm[8][256];
    const int t  = threadIdx.x;
    const int b  = blockIdx.x;
    const int rg = t >> 5;
    const int c8 = (t & 31) * 8;
    float s[8];
#pragma unroll
    for (int j = 0; j < 8; ++j) s[j] = 0.f;
    for (int i2 = 0; i2 < 16; ++i2) {
        const int row = b * 128 + i2 * 8 + rg;
        if (row < N_NODES) {
            const bf16x8 v = *(const bf16x8*)(hb + (size_t)row * H_C + c8);
#pragma unroll
            for (int j = 0; j < 8; ++j) s[j] += (float)v[j];
        }
    }
#pragma unroll
    for (int j = 0; j < 8; ++j) sm[rg][c8 + j] = s[j];
    __syncthreads();
    float tot = 0.f;
#pragma unroll
    for (int g = 0; g < 8; ++g) tot += sm[g][t];
    part[b * H_C + t] = tot;
}

__global__ __launch_bounds__(256)
void reduce_final(const float* __restrict__ part,
                  const float* __restrict__ W_fc,
                  const float* __restrict__ b_fc,
                  float* __restrict__ out)
{
    __shared__ float sm[256];
    const int t = threadIdx.x;
    float s = 0.f;
    for (int j = 0; j < 256; ++j) s += part[j * H_C + t];
    s = s * (1.0f / (float)N_NODES) * W_fc[t];
    sm[t] = s;
    __syncthreads();
    for (int st = 128; st > 0; st >>= 1) {
        if (t < st) sm[t] += sm[t + st];
        __syncthreads();
    }
    if (t == 0) out[0] = sm[0] + b_fc[0];
}

extern "C" void kernel_launch(void* const* d_in, const int* in_sizes, int n_in,
                              void* d_out, int out_size, void* d_ws, size_t ws_size,
                              hipStream_t stream)
{
    const float* x    = (const float*)d_in[0];
    // d_in[1] = edge_index — tree is implicit, unused
    const float* W_ih = (const float*)d_in[2];
    const float* W_hh = (const float*)d_in[3];
    const float* b_ih = (const float*)d_in[4];
    const float* b_hh = (const float*)d_in[5];
    const float* W_fc = (const float*)d_in[6];
    const float* b_fc = (const float*)d_in[7];
    float* out = (float*)d_out;

    // workspace layout (16B aligned). Base layout identical to round-1 (~86.8 MB),
    // xb (bf16 x) appended only if ws allows (~120.3 MB total).
    char* w = (char*)d_ws;
    size_t used = 0;
    __bf16* hb   = (__bf16*)(w + used); used += (size_t)N_NODES * H_C * 2;
    float*  c    = (float*)(w + used);  used += (size_t)N_NODES * H_C * 4;
    __bf16* gx   = (__bf16*)(w + used); used += (size_t)N_LEAF0 * H_C * 4 * 2;
    __bf16* wihb = (__bf16*)(w + used); used += (size_t)4 * H_C * IN_C * 2;
    __bf16* whhb = (__bf16*)(w + used); used += (size_t)4 * H_C * H_C * 2;
    float*  part = (float*)(w + used);  used += (size_t)256 * H_C * 4;
    __bf16* xb   = (__bf16*)(w + used);
    const size_t need_xb = used + (size_t)N_NODES * IN_C * 2 + 1024;
    const bool have_xb = (ws_size >= need_xb);

    // one fused conversion pass (x converted only when it fits in ws)
    {
        const int n8i = (4 * H_C * IN_C) / 8;           // 65536
        const int n8h = (4 * H_C * H_C) / 8;            // 32768
        const int n8x = have_xb ? (N_NODES * IN_C) / 8 : 0;  // 2097088
        conv3<<<2048, 256, 0, stream>>>(W_ih, wihb, n8i, W_hh, whhb, n8h, x, xb, n8x);
    }

    // bulk: x@W_ih^T for all nodes; leaves fully solved, internal -> gates_x
    if (have_xb)
        bulk_xw2<<<2048, 256, 0, stream>>>(xb, wihb, b_ih, b_hh, hb, c, gx);
    else
        bulk_xw<<<2048, 256, 0, stream>>>(x, wihb, b_ih, b_hh, hb, c, gx);

    // all 14 levels + reduce in one cooperative kernel
    {
        const __bf16* a0 = whhb; const float* a1 = b_ih; const float* a2 = b_hh;
        const __bf16* a3 = gx;   __bf16* a4 = hb;        float* a5 = c;
        const float* a6 = W_fc;  const float* a7 = b_fc; float* a8 = part;
        float* a9 = out;
        void* targs[] = {&a0, &a1, &a2, &a3, &a4, &a5, &a6, &a7, &a8, &a9};
        hipError_t e = hipLaunchCooperativeKernel((const void*)levels_coop,
                                                  dim3(512), dim3(256), targs, 0, stream);
        if (e != hipSuccess) {
            for (int d = 13; d >= 0; --d) {
                const int n  = 1 << d;
                const int lo = n - 1;
                const int nm = (n + 127) / 128;
                level_hw<<<nm * 8, 256, 0, stream>>>(whhb, b_ih, b_hh, gx, hb, c, lo, n);
            }
            reduce_rows<<<256, 256, 0, stream>>>(hb, part);
            reduce_final<<<1, 256, 0, stream>>>(part, W_fc, b_fc, out);
        }
    }
}

// Round 3
// 465.305 us; speedup vs baseline: 2.4748x; 2.4748x over previous
//
#include <hip/hip_runtime.h>
#include <hip/hip_cooperative_groups.h>
#include <math.h>

namespace cg = cooperative_groups;

// TreeLSTM, complete binary tree N = 2^15-1 (implicit: children(i)=2i+1,2i+2).
// Round 6: revert round-2's two losing bets (512-block coop: 62us/grid.sync;
// gload-A bulk: slower), keep its verified pieces (BK=64 level GEMM, gx
// [node][ch][gate] layout). New: (a) tail coop (8 blocks, cheap syncs) extended
// to levels 9..0 via 64-row chunk loops; (b) pooled mean folded into producers
// via hsum atomics (kills both reduce dispatches + 16.8MB re-read); (c) bulk
// T14 register-prefetch of next k-step x. 7 dispatches total.

#define N_NODES 32767
#define N_LEAF0 16383     // first leaf node index
#define IN_C    512
#define H_C     256

typedef __bf16 bf16x8 __attribute__((ext_vector_type(8)));
typedef __bf16 bf16x4 __attribute__((ext_vector_type(4)));
typedef float  f32x4  __attribute__((ext_vector_type(4)));

__device__ __forceinline__ void gload_lds16(const void* g, void* l) {
    __builtin_amdgcn_global_load_lds(
        (const __attribute__((address_space(1))) unsigned int*)g,
        (__attribute__((address_space(3))) unsigned int*)l,
        16, 0, 0);
}

__device__ __forceinline__ float fast_rcp(float x) { return __builtin_amdgcn_rcpf(x); }
__device__ __forceinline__ float sigm(float x)     { return fast_rcp(1.f + __expf(-x)); }
__device__ __forceinline__ float tanh_fast(float x){ return 2.f * fast_rcp(1.f + __expf(-2.f * x)) - 1.f; }

// ---- fused weight converter (W_ih | W_hh) + hsum zeroing ----
__global__ __launch_bounds__(256)
void conv2(const float* __restrict__ a, __bf16* __restrict__ da, int n8a,
           const float* __restrict__ b, __bf16* __restrict__ db, int n8b,
           float* __restrict__ hsum)
{
    if (blockIdx.x == 0 && threadIdx.x < 256) hsum[threadIdx.x] = 0.f;
    const int total = n8a + n8b;
    for (int i = blockIdx.x * 256 + threadIdx.x; i < total; i += gridDim.x * 256) {
        const float* s; __bf16* d; int j;
        if (i < n8a) { s = a; d = da; j = i; }
        else         { s = b; d = db; j = i - n8a; }
        const float4* s4 = (const float4*)s;
        const float4 v0 = s4[2 * j];
        const float4 v1 = s4[2 * j + 1];
        bf16x8 o;
        o[0] = (__bf16)v0.x; o[1] = (__bf16)v0.y; o[2] = (__bf16)v0.z; o[3] = (__bf16)v0.w;
        o[4] = (__bf16)v1.x; o[5] = (__bf16)v1.y; o[6] = (__bf16)v1.z; o[7] = (__bf16)v1.w;
        *(bf16x8*)(d + 8 * j) = o;
    }
}

// ---- bulk: acc = x @ W_ih^T for ALL nodes (inline fp32->bf16 A staging,
// T14 reg-prefetch of next k-step). Leaves fully solved; internal -> gx.
__global__ __launch_bounds__(256)
void bulk_xw(const float* __restrict__ x,
             const __bf16* __restrict__ wih,
             const float* __restrict__ b_ih,
             const float* __restrict__ b_hh,
             __bf16* __restrict__ hb,
             float* __restrict__ c,
             __bf16* __restrict__ gx,
             float* __restrict__ hsum)
{
    __shared__ __bf16 As[128 * 64];
    __shared__ __bf16 Bs[128 * 64];
    __shared__ float  hs[32];

    const int t    = threadIdx.x;
    const int lane = t & 63;
    const int wv   = t >> 6;
    const int wm   = wv >> 1;
    const int wn   = wv & 1;
    const int quad = lane >> 4;
    const int l15  = lane & 15;

    if (t < 32) hs[t] = 0.f;

    const int i  = blockIdx.x;
    const int cb = (i >> 3) & 7;
    const int mt = (i & 7) | ((i >> 6) << 3);
    const int m0 = mt * 128;

    f32x4 acc[4][4];
#pragma unroll
    for (int mi = 0; mi < 4; ++mi)
#pragma unroll
        for (int ni = 0; ni < 4; ++ni) acc[mi][ni] = (f32x4)0.f;

    // A-prefetch state: this thread stages row (t>>1), k-halves kh..kh+31
    const int arow = t >> 1;
    const int kh   = (t & 1) * 32;
    const int anode = min(m0 + arow, N_NODES - 1);
    const float* xrow = x + (size_t)anode * IN_C + kh;
    float4 xr[8];
#pragma unroll
    for (int j = 0; j < 8; ++j) xr[j] = ((const float4*)xrow)[j];   // k0 = 0

    for (int k0 = 0; k0 < IN_C; k0 += 64) {
        // ---- stage B: W_ih slab via gload_lds, source pre-XOR-swizzled ----
#pragma unroll
        for (int e = 0; e < 4; ++e) {
            const int ch = (wv * 4 + e) * 64 + lane;
            const int nl = ch >> 3;
            const int k8 = (ch & 7) ^ (nl & 7);
            const int q  = (nl >> 4) & 3;
            const int cc = (nl & 15) | ((nl >> 6) << 4);
            const int grow = q * H_C + cb * 32 + cc;
            gload_lds16(wih + (size_t)grow * IN_C + k0 + k8 * 8,
                        (char*)Bs + (wv * 4 + e) * 1024);
        }
        // ---- stage A: convert prefetched regs -> XOR-swizzled ds_write ----
#pragma unroll
        for (int j = 0; j < 4; ++j) {
            const float4 v0 = xr[2 * j], v1 = xr[2 * j + 1];
            bf16x8 o;
            o[0] = (__bf16)v0.x; o[1] = (__bf16)v0.y; o[2] = (__bf16)v0.z; o[3] = (__bf16)v0.w;
            o[4] = (__bf16)v1.x; o[5] = (__bf16)v1.y; o[6] = (__bf16)v1.z; o[7] = (__bf16)v1.w;
            const int cs = ((kh >> 3) + j) ^ (arow & 7);
            *(bf16x8*)(As + arow * 64 + cs * 8) = o;
        }
        __syncthreads();
        // ---- T14: issue next k-step's x loads; they fly under the MFMAs ----
        if (k0 + 64 < IN_C) {
            const float4* xs = (const float4*)(xrow + k0 + 64);
#pragma unroll
            for (int j = 0; j < 8; ++j) xr[j] = xs[j];
        }
#pragma unroll
        for (int ks = 0; ks < 2; ++ks) {
            bf16x8 af[4], bfr[4];
#pragma unroll
            for (int mi = 0; mi < 4; ++mi) {
                const int row = wm * 64 + mi * 16 + l15;
                af[mi] = *(const bf16x8*)(As + row * 64 + (((ks * 4 + quad) ^ (row & 7)) << 3));
            }
#pragma unroll
            for (int ni = 0; ni < 4; ++ni) {
                const int row = wn * 64 + ni * 16 + l15;
                bfr[ni] = *(const bf16x8*)(Bs + row * 64 + (((ks * 4 + quad) ^ (row & 7)) << 3));
            }
#pragma unroll
            for (int mi = 0; mi < 4; ++mi)
#pragma unroll
                for (int ni = 0; ni < 4; ++ni)
                    acc[mi][ni] = __builtin_amdgcn_mfma_f32_16x16x32_bf16(
                        af[mi], bfr[ni], acc[mi][ni], 0, 0, 0);
        }
        __syncthreads();
    }

    const int CH = cb * 32 + wn * 16 + l15;
    float bs4[4];
#pragma unroll
    for (int q = 0; q < 4; ++q) bs4[q] = b_ih[q * H_C + CH] + b_hh[q * H_C + CH];

    float lh = 0.f;
#pragma unroll
    for (int mi = 0; mi < 4; ++mi) {
#pragma unroll
        for (int r = 0; r < 4; ++r) {
            const int m = m0 + wm * 64 + mi * 16 + quad * 4 + r;
            if (m >= N_NODES) continue;
            if (m >= N_LEAF0) {
                const float gi = sigm(acc[mi][0][r] + bs4[0]);
                const float gg = tanh_fast(acc[mi][2][r] + bs4[2]);
                const float go = sigm(acc[mi][3][r] + bs4[3]);
                const float cn = gi * gg;
                const float hn = go * tanh_fast(cn);
                c[(size_t)m * H_C + CH] = cn;
                hb[(size_t)m * H_C + CH] = (__bf16)hn;
                lh += hn;
            } else {
                bf16x4 o;
#pragma unroll
                for (int q = 0; q < 4; ++q) o[q] = (__bf16)acc[mi][q][r];
                *(bf16x4*)(gx + ((size_t)m * H_C + CH) * 4) = o;
            }
        }
    }
    atomicAdd(&hs[wn * 16 + l15], lh);
    __syncthreads();
    if (t < 32) atomicAdd(&hsum[cb * 32 + t], hs[t]);
}

// ---- one level-tile: gates = gates_x + mean_h @ W_hh^T (K=256, BK=64) ----
__device__ __forceinline__ void level_tile(
    const __bf16* __restrict__ whh, const float* __restrict__ b_ih,
    const float* __restrict__ b_hh, const __bf16* __restrict__ gx,
    __bf16* __restrict__ hb, float* __restrict__ c, float* __restrict__ hsum,
    __bf16* As, __bf16* Bs, float* hs, int lo, int n, int cb, int m0)
{
    const int t    = threadIdx.x;
    const int lane = t & 63;
    const int wv   = t >> 6;
    const int wm   = wv >> 1;
    const int wn   = wv & 1;
    const int quad = lane >> 4;
    const int l15  = lane & 15;

    f32x4 acc[4][4];
#pragma unroll
    for (int mi = 0; mi < 4; ++mi)
#pragma unroll
        for (int ni = 0; ni < 4; ++ni) acc[mi][ni] = (f32x4)0.f;

    for (int k0 = 0; k0 < H_C; k0 += 64) {
#pragma unroll
        for (int e = 0; e < 4; ++e) {
            const int ch = (wv * 4 + e) * 64 + lane;
            const int nl = ch >> 3;
            const int k8 = (ch & 7) ^ (nl & 7);
            const int q  = (nl >> 4) & 3;
            const int cc = (nl & 15) | ((nl >> 6) << 4);
            const int grow = q * H_C + cb * 32 + cc;
            gload_lds16(whh + (size_t)grow * H_C + k0 + k8 * 8,
                        (char*)Bs + (wv * 4 + e) * 1024);
        }
        {
            const int row  = t >> 1;
            const int kh   = (t & 1) * 32;
            const int node = lo + m0 + row;
            const int k2   = k0 + kh;
            const bf16x8* hl = (const bf16x8*)(hb + (size_t)(2 * node + 1) * H_C + k2);
            const bf16x8* hr = (const bf16x8*)(hb + (size_t)(2 * node + 2) * H_C + k2);
#pragma unroll
            for (int j = 0; j < 4; ++j) {
                const bf16x8 a = hl[j], b = hr[j];
                bf16x8 o;
#pragma unroll
                for (int e2 = 0; e2 < 8; ++e2)
                    o[e2] = (__bf16)(0.5f * ((float)a[e2] + (float)b[e2]));
                const int cs = ((kh >> 3) + j) ^ (row & 7);
                *(bf16x8*)(As + row * 64 + cs * 8) = o;
            }
        }
        __syncthreads();
#pragma unroll
        for (int ks = 0; ks < 2; ++ks) {
            bf16x8 af[4], bfr[4];
#pragma unroll
            for (int mi = 0; mi < 4; ++mi) {
                const int row = wm * 64 + mi * 16 + l15;
                af[mi] = *(const bf16x8*)(As + row * 64 + (((ks * 4 + quad) ^ (row & 7)) << 3));
            }
#pragma unroll
            for (int ni = 0; ni < 4; ++ni) {
                const int row = wn * 64 + ni * 16 + l15;
                bfr[ni] = *(const bf16x8*)(Bs + row * 64 + (((ks * 4 + quad) ^ (row & 7)) << 3));
            }
#pragma unroll
            for (int mi = 0; mi < 4; ++mi)
#pragma unroll
                for (int ni = 0; ni < 4; ++ni)
                    acc[mi][ni] = __builtin_amdgcn_mfma_f32_16x16x32_bf16(
                        af[mi], bfr[ni], acc[mi][ni], 0, 0, 0);
        }
        __syncthreads();
    }

    const int CH = cb * 32 + wn * 16 + l15;
    float bs4[4];
#pragma unroll
    for (int q = 0; q < 4; ++q) bs4[q] = b_ih[q * H_C + CH] + b_hh[q * H_C + CH];

    float lh = 0.f;
#pragma unroll
    for (int mi = 0; mi < 4; ++mi) {
#pragma unroll
        for (int r = 0; r < 4; ++r) {
            const int m = m0 + wm * 64 + mi * 16 + quad * 4 + r;
            if (m < n) {
                const int node = lo + m;
                const bf16x4 gv = *(const bf16x4*)(gx + ((size_t)node * H_C + CH) * 4);
                const float gi = sigm(acc[mi][0][r] + (float)gv[0] + bs4[0]);
                const float gf = sigm(acc[mi][1][r] + (float)gv[1] + bs4[1]);
                const float gg = tanh_fast(acc[mi][2][r] + (float)gv[2] + bs4[2]);
                const float go = sigm(acc[mi][3][r] + (float)gv[3] + bs4[3]);
                const float mc = 0.5f * (c[(size_t)(2 * node + 1) * H_C + CH] +
                                         c[(size_t)(2 * node + 2) * H_C + CH]);
                const float cn = gf * mc + gi * gg;
                const float hn = go * tanh_fast(cn);
                c[(size_t)node * H_C + CH] = cn;
                hb[(size_t)node * H_C + CH] = (__bf16)hn;
                lh += hn;
            }
        }
    }
    atomicAdd(&hs[wn * 16 + l15], lh);
    __syncthreads();
    if (t < 32) atomicAdd(&hsum[cb * 32 + t], hs[t]);
}

// ---- standalone per-level kernel (levels 13..10 and fallback) ----
__global__ __launch_bounds__(256)
void level_hw(const __bf16* __restrict__ whh,
              const float* __restrict__ b_ih,
              const float* __restrict__ b_hh,
              const __bf16* __restrict__ gx,
              __bf16* __restrict__ hb,
              float* __restrict__ c,
              float* __restrict__ hsum,
              int lo, int n)
{
    __shared__ __bf16 As[128 * 64];
    __shared__ __bf16 Bs[128 * 64];
    __shared__ float  hs[32];
    if (threadIdx.x < 32) hs[threadIdx.x] = 0.f;
    const int i = blockIdx.x;
    int cb, mt;
    if (gridDim.x >= 64) { cb = (i >> 3) & 7; mt = (i & 7) | ((i >> 6) << 3); }
    else                 { cb = i & 7;        mt = i >> 3; }
    level_tile(whh, b_ih, b_hh, gx, hb, c, hsum, As, Bs, hs, lo, n, cb, mt * 128);
}

// ---- cooperative tail: levels 9..0 + final FC. grid(8): block cb owns
// channels [cb*32,cb*32+32), all gates; 64-row chunks for levels 9..7.
__global__ __launch_bounds__(256, 1)
void tail_levels(const __bf16* __restrict__ whh,
                 const float* __restrict__ b_ih,
                 const float* __restrict__ b_hh,
                 const __bf16* __restrict__ gx,
                 __bf16* __restrict__ hb,
                 float* __restrict__ c,
                 float* __restrict__ hsum,
                 const float* __restrict__ W_fc,
                 const float* __restrict__ b_fc,
                 float* __restrict__ out)
{
    __shared__ __bf16 Ws[128][264];                    // 67.6 KB
    __shared__ __align__(16) char UAG[64 * 264 * 2];   // 33.8 KB: As | Gs alias
    __shared__ float cl[2][64][33];                    // 16.9 KB c ping-pong
    __shared__ float hs[32];
    __shared__ float fm[256];

    const int t    = threadIdx.x;
    const int cb   = blockIdx.x;
    const int lane = t & 63;
    const int wq   = t >> 6;        // wave index == gate q
    const int quad = lane >> 4;
    const int l15  = lane & 15;

    auto As = (__bf16(*)[264])UAG;
    auto Gs = (float(*)[64][33])UAG;

    if (t < 32) hs[t] = 0.f;

    // stage W_hh slab once: Ws row q*32+cc <- whh row q*256 + cb*32 + cc
    {
        const int row = t >> 1;
        const int k0  = (t & 1) * 128;
        const int q   = row >> 5, cc = row & 31;
        const __bf16* src = whh + (size_t)(q * H_C + cb * 32 + cc) * H_C + k0;
#pragma unroll
        for (int j = 0; j < 16; ++j)
            *(bf16x8*)(&Ws[row][k0 + 8 * j]) = *(const bf16x8*)(src + 8 * j);
    }
    const int ecc = t & 31;
    const int erg = t >> 5;
    const int CH  = cb * 32 + ecc;
    float bsq[4];
#pragma unroll
    for (int q = 0; q < 4; ++q) bsq[q] = b_ih[q * H_C + CH] + b_hh[q * H_C + CH];
    float th = 0.f;

    cg::grid_group grid = cg::this_grid();

    for (int d = 9; d >= 0; --d) {
        const int n   = 1 << d;
        const int lo  = n - 1;
        const int pp  = d & 1;
        const int nck = (n + 63) >> 6;
        for (int ck = 0; ck < nck; ++ck) {
            const int rbase = ck * 64;
            const int rows  = (n - rbase < 64) ? (n - rbase) : 64;
            __syncthreads();   // prev chunk's Gs reads done before As overwrite
            // ---- stage A: mean-of-children h, 64 rows ----
            {
                const int row  = t >> 2;
                const int kb   = (t & 3) * 64;
                const int node = lo + rbase + row;
                const bf16x8* hl = (const bf16x8*)(hb + (size_t)(2 * node + 1) * H_C + kb);
                const bf16x8* hr = (const bf16x8*)(hb + (size_t)(2 * node + 2) * H_C + kb);
#pragma unroll
                for (int j = 0; j < 8; ++j) {
                    const bf16x8 a = hl[j], b = hr[j];
                    bf16x8 o;
#pragma unroll
                    for (int e = 0; e < 8; ++e)
                        o[e] = (__bf16)(0.5f * ((float)a[e] + (float)b[e]));
                    *(bf16x8*)(&As[row][kb + 8 * j]) = o;
                }
            }
            __syncthreads();
            // ---- MFMA: wave wq -> gate wq, 64 rows x 32 ch, K=256 resident ----
            f32x4 acc[4][2];
#pragma unroll
            for (int mi = 0; mi < 4; ++mi)
#pragma unroll
                for (int ni = 0; ni < 2; ++ni) acc[mi][ni] = (f32x4)0.f;
            for (int kk = 0; kk < 8; ++kk) {
#pragma unroll
                for (int mi = 0; mi < 4; ++mi) {
                    const bf16x8 af = *(const bf16x8*)(&As[mi * 16 + l15][kk * 32 + quad * 8]);
#pragma unroll
                    for (int ni = 0; ni < 2; ++ni) {
                        const bf16x8 bf_ = *(const bf16x8*)(&Ws[wq * 32 + ni * 16 + l15][kk * 32 + quad * 8]);
                        acc[mi][ni] = __builtin_amdgcn_mfma_f32_16x16x32_bf16(af, bf_, acc[mi][ni], 0, 0, 0);
                    }
                }
            }
            __syncthreads();   // As consumption done; UAG becomes Gs
#pragma unroll
            for (int mi = 0; mi < 4; ++mi)
#pragma unroll
                for (int ni = 0; ni < 2; ++ni)
#pragma unroll
                    for (int r = 0; r < 4; ++r)
                        Gs[wq][mi * 16 + quad * 4 + r][ni * 16 + l15] = acc[mi][ni][r];
            __syncthreads();
            // ---- cell epilogue ----
            for (int r = erg; r < rows; r += 8) {
                const int rr   = rbase + r;
                const int node = lo + rr;
                const bf16x4 gv = *(const bf16x4*)(gx + ((size_t)node * H_C + CH) * 4);
                float g[4];
#pragma unroll
                for (int q = 0; q < 4; ++q) g[q] = Gs[q][r][ecc] + (float)gv[q] + bsq[q];
                const float gi = sigm(g[0]);
                const float gf = sigm(g[1]);
                const float gg = tanh_fast(g[2]);
                const float go = sigm(g[3]);
                float mc;
                if (d >= 6)   // children's c lives in global
                    mc = 0.5f * (c[(size_t)(2 * node + 1) * H_C + CH] +
                                 c[(size_t)(2 * node + 2) * H_C + CH]);
                else
                    mc = 0.5f * (cl[pp ^ 1][2 * rr][ecc] + cl[pp ^ 1][2 * rr + 1][ecc]);
                const float cn = gf * mc + gi * gg;
                const float hn = go * tanh_fast(cn);
                if (d >= 7) c[(size_t)node * H_C + CH] = cn;   // level-6..8 read it
                else        cl[pp][rr][ecc] = cn;              // rr < 64 here
                hb[(size_t)node * H_C + CH] = (__bf16)hn;
                th += hn;
            }
        }
        grid.sync();   // h (and c) of level d visible before level d-1
    }

    // ---- flush h partial sums, then final FC in block 0 ----
    atomicAdd(&hs[ecc], th);
    __syncthreads();
    if (t < 32) atomicAdd(&hsum[cb * 32 + t], hs[t]);
    grid.sync();

    if (cb == 0) {
        fm[t] = hsum[t] * (1.0f / (float)N_NODES) * W_fc[t];
        __syncthreads();
        for (int st = 128; st > 0; st >>= 1) {
            if (t < st) fm[t] += fm[t + st];
            __syncthreads();
        }
        if (t == 0) out[0] = fm[0] + b_fc[0];
    }
}

// ---- fallback final FC (if coop launch rejected) ----
__global__ __launch_bounds__(256)
void final_out(const float* __restrict__ hsum,
               const float* __restrict__ W_fc,
               const float* __restrict__ b_fc,
               float* __restrict__ out)
{
    __shared__ float fm[256];
    const int t = threadIdx.x;
    fm[t] = hsum[t] * (1.0f / (float)N_NODES) * W_fc[t];
    __syncthreads();
    for (int st = 128; st > 0; st >>= 1) {
        if (t < st) fm[t] += fm[t + st];
        __syncthreads();
    }
    if (t == 0) out[0] = fm[0] + b_fc[0];
}

extern "C" void kernel_launch(void* const* d_in, const int* in_sizes, int n_in,
                              void* d_out, int out_size, void* d_ws, size_t ws_size,
                              hipStream_t stream)
{
    const float* x    = (const float*)d_in[0];
    // d_in[1] = edge_index — tree is implicit, unused
    const float* W_ih = (const float*)d_in[2];
    const float* W_hh = (const float*)d_in[3];
    const float* b_ih = (const float*)d_in[4];
    const float* b_hh = (const float*)d_in[5];
    const float* W_fc = (const float*)d_in[6];
    const float* b_fc = (const float*)d_in[7];
    float* out = (float*)d_out;

    // workspace layout (16B aligned), ~85.5 MB
    char* w = (char*)d_ws;
    size_t used = 0;
    __bf16* hb   = (__bf16*)(w + used); used += (size_t)N_NODES * H_C * 2;       // 16.78 MB
    float*  c    = (float*)(w + used);  used += (size_t)N_NODES * H_C * 4;       // 33.55 MB
    __bf16* gx   = (__bf16*)(w + used); used += (size_t)N_LEAF0 * H_C * 4 * 2;   // 33.55 MB
    __bf16* wihb = (__bf16*)(w + used); used += (size_t)4 * H_C * IN_C * 2;      // 1.05 MB
    __bf16* whhb = (__bf16*)(w + used); used += (size_t)4 * H_C * H_C * 2;       // 0.52 MB
    float*  hsum = (float*)(w + used);  used += 256 * 4;

    // 1) weights -> bf16, zero hsum
    {
        const int n8i = (4 * H_C * IN_C) / 8;   // 65536
        const int n8h = (4 * H_C * H_C) / 8;    // 32768
        conv2<<<384, 256, 0, stream>>>(W_ih, wihb, n8i, W_hh, whhb, n8h, hsum);
    }

    // 2) bulk x@W_ih^T (leaves solved; internal -> gx; leaf h-sums -> hsum)
    bulk_xw<<<2048, 256, 0, stream>>>(x, wihb, b_ih, b_hh, hb, c, gx, hsum);

    // 3) levels 13..10 standalone
    for (int d = 13; d >= 10; --d) {
        const int n  = 1 << d;
        const int lo = n - 1;
        const int nm = (n + 127) / 128;
        level_hw<<<nm * 8, 256, 0, stream>>>(whhb, b_ih, b_hh, gx, hb, c, hsum, lo, n);
    }

    // 4) levels 9..0 + final FC: one 8-block cooperative kernel
    {
        const __bf16* a0 = whhb; const float* a1 = b_ih; const float* a2 = b_hh;
        const __bf16* a3 = gx;   __bf16* a4 = hb;        float* a5 = c;
        float* a6 = hsum;        const float* a7 = W_fc; const float* a8 = b_fc;
        float* a9 = out;
        void* targs[] = {&a0, &a1, &a2, &a3, &a4, &a5, &a6, &a7, &a8, &a9};
        hipError_t e = hipLaunchCooperativeKernel((const void*)tail_levels,
                                                  dim3(8), dim3(256), targs, 0, stream);
        if (e != hipSuccess) {
            for (int d = 9; d >= 0; --d) {
                const int n  = 1 << d;
                const int lo = n - 1;
                const int nm = (n + 127) / 128;
                level_hw<<<nm * 8, 256, 0, stream>>>(whhb, b_ih, b_hh, gx, hb, c, hsum, lo, n);
            }
            final_out<<<1, 256, 0, stream>>>(hsum, W_fc, b_fc, out);
        }
    }
}